// Round 7
// baseline (37.684 us; speedup 1.0000x reference)
//
#include <hip/hip_runtime.h>

typedef __attribute__((ext_vector_type(8))) short bf16x8;
typedef __attribute__((ext_vector_type(4))) float f32x4;

#define EPS 1e-5f
#define K2L 2.8853900817779268f   // 2*log2(e): folds exp(2y) -> exp2(y*K2L)

// ws layout: frag blocks (182 x 1KB bf16) then fp32 ST region
#define N_FRAG_BLOCKS 182
#define WSB_LEAF 0      // 64 blocks: leaf l
#define WSB_MID  64     // 80 blocks: m*10 + tt*5 + s
#define WSB_ROOT 144    // 36 blocks: tt*9 + s
#define WSB_HEAD 180    // 2 blocks: s
#define ST_SL 0
#define ST_TL 1024
#define ST_SM 2048
#define ST_TM 2304
#define ST_SR 2560
#define ST_TR 2624
#define WS_ST_BYTE_OFF (N_FRAG_BLOCKS * 1024)

__device__ __forceinline__ unsigned short f2bf(float f) {  // RNE float->bf16
    unsigned u = __float_as_uint(f);
    unsigned r = u + 0x7fffu + ((u >> 16) & 1u);
    return (unsigned short)(r >> 16);
}

__device__ __forceinline__ unsigned pack2bf(float a, float b) {
    return (unsigned)f2bf(a) | ((unsigned)f2bf(b) << 16);
}

__device__ __forceinline__ bf16x8 pack8(float4 a, float4 b) {
    union { unsigned u[4]; bf16x8 v; } r;
    r.u[0] = pack2bf(a.x, a.y); r.u[1] = pack2bf(a.z, a.w);
    r.u[2] = pack2bf(b.x, b.y); r.u[3] = pack2bf(b.z, b.w);
    return r.v;
}

// BN+tanh with pre-folded scale: arg = acc*S' + T' (S',T' carry 2*log2e)
__device__ __forceinline__ float bn_act(float acc, float Sp, float Tp) {
    float e = exp2f(fmaf(acc, Sp, Tp));
    float r = __builtin_amdgcn_rcpf(e + 1.0f);
    return fmaf(-2.0f, r, 1.0f);
}

__device__ __forceinline__ void gl_lds16(const float* g, float* l) {
    __builtin_amdgcn_global_load_lds(
        (const __attribute__((address_space(1))) unsigned int*)g,
        (__attribute__((address_space(3))) unsigned int*)l, 16, 0, 0);
}

#define FENCE() asm volatile("" ::: "memory")
#define BARRIER() do { FENCE(); __builtin_amdgcn_s_barrier(); FENCE(); } while (0)

// ---------------- prep: fragment-ordered bf16 weights + folded BN ----------
__global__ void ontology_prep(
    const float* __restrict__ Wl, const float* __restrict__ Wm,
    const float* __restrict__ Wr, const float* __restrict__ Wh,
    const float* __restrict__ bl, const float* __restrict__ gl,
    const float* __restrict__ betal, const float* __restrict__ ml,
    const float* __restrict__ vl,
    const float* __restrict__ bm, const float* __restrict__ gm,
    const float* __restrict__ betam, const float* __restrict__ mm,
    const float* __restrict__ vm,
    const float* __restrict__ br, const float* __restrict__ gr,
    const float* __restrict__ betar, const float* __restrict__ mr,
    const float* __restrict__ vr,
    unsigned short* __restrict__ wsFrag, float* __restrict__ wsST)
{
    const int b = blockIdx.x;
    const int t = threadIdx.x;
    if (b < N_FRAG_BLOCKS) {
        // A'-frag (transposed weights): lane t holds A'[row=t&15][k=(t>>4)*8+i]
        const int row = t & 15, g = t >> 4;
        unsigned short vals[8];
        #pragma unroll
        for (int i = 0; i < 8; ++i) {
            const int k = g * 8 + i;
            float v = 0.f;
            if (b < 64) {                       // leaf l: pair-packed K
                const int l = b;
                if ((l & 1) == 0) { if (k < 16)  v = Wl[l * 256 + k * 16 + row]; }
                else              { if (k >= 16) v = Wl[l * 256 + (k - 16) * 16 + row]; }
            } else if (b < 144) {               // mid: m*10 + tt*5 + s
                const int idx = b - 64, m = idx / 10, rem = idx % 10;
                const int tt = rem / 5, s = rem % 5;
                const int krow = s * 32 + k;
                if (krow < 144) v = Wm[m * 4608 + krow * 32 + tt * 16 + row];
            } else if (b < 180) {               // root: tt*9 + s
                const int idx = b - 144, tt = idx / 9, s = idx % 9;
                if (s == 0) { if (k < 16) v = Wr[k * 64 + tt * 16 + row]; }
                else { const int krow = 16 + (s - 1) * 32 + k;
                       v = Wr[krow * 64 + tt * 16 + row]; }
            } else {                            // head
                const int s = b - 180, krow = s * 32 + k;
                if (row < 10) v = Wh[krow * 10 + row];
            }
            vals[i] = f2bf(v);
        }
        #pragma unroll
        for (int i = 0; i < 8; ++i) wsFrag[b * 512 + t * 8 + i] = vals[i];
    } else if (b == N_FRAG_BLOCKS) {            // leaf ST (1024), folded by K2L
        for (int i = 0; i < 16; ++i) {
            const int id = t + 64 * i;
            const float S = gl[id] * rsqrtf(vl[id] + EPS);
            wsST[ST_SL + id] = S * K2L;
            wsST[ST_TL + id] = ((bl[id] - ml[id]) * S + betal[id]) * K2L;
        }
    } else if (b == N_FRAG_BLOCKS + 1) {        // mid ST (256)
        for (int i = 0; i < 4; ++i) {
            const int id = t + 64 * i;
            const float S = gm[id] * rsqrtf(vm[id] + EPS);
            wsST[ST_SM + id] = S * K2L;
            wsST[ST_TM + id] = ((bm[id] - mm[id]) * S + betam[id]) * K2L;
        }
    } else {                                     // root ST (64)
        const int id = t;
        const float S = gr[id] * rsqrtf(vr[id] + EPS);
        wsST[ST_SR + id] = S * K2L;
        wsST[ST_TR + id] = ((br[id] - mr[id]) * S + betar[id]) * K2L;
    }
}

// ---------------- main fused MFMA kernel -----------------------------------
// Block = 256 thr = 4 waves = one 16-sample tile. Lockstep over mids m=0..7:
//   wave w: leaf pair w (2 MFMA); waves 2,3: mid col-tiles; each wave: 1 root
//   K-step. x for phase m+2 DMA-staged via global_load_lds (sequential 512B
//   spans, XOR-swizzled source so linear-LDS reads are conflict-free).
// Counted per-wave vmcnt + raw s_barrier (no vmcnt(0) drain). 2 barriers/phase.
__global__ __launch_bounds__(256, 4) void ontology_mfma(
    const float* __restrict__ x,
    const unsigned short* __restrict__ wsFrag,
    const float* __restrict__ wsST,
    const float* __restrict__ bh,
    float* __restrict__ out)
{
    __shared__ __align__(16) float xbuf[2][2048];        // 16 KB: leaf x dbuf
    __shared__ __align__(16) float xtail[2304];          // 9 KB: x cols 1024..1168
    __shared__ __align__(16) unsigned short mid_in[16][168];  // 5.25 KB
    __shared__ __align__(16) unsigned short hm[2][16][40];    // 2.5 KB
    unsigned short (*hr)[72] = (unsigned short (*)[72])&xbuf[0][0]; // alias (dead post-loop)

    const int tid  = threadIdx.x;
    const int w    = tid >> 6;
    const int lane = tid & 63;
    const int c    = lane & 15;       // sample within tile
    const int g    = lane >> 4;       // k/feat group
    const int rowbase = blockIdx.x * 16;
    const float* xbase = x + (size_t)rowbase * 1168;

    const float* Sl = wsST + ST_SL; const float* Tl = wsST + ST_TL;
    const float* Sm = wsST + ST_SM; const float* Tm = wsST + ST_TM;
    const float* Sr = wsST + ST_SR; const float* Tr = wsST + ST_TR;

    // per-lane swizzled source offsets for this wave's 2 stage chunks
    // chunk k covers rows 2k,2k+1; lds granule gi=k*64+lane; row=gi>>5, gc=gi&31
    // source granule = gc ^ (row&7)  (inverse-swizzle; reads XOR the same way)
    int offk[2];
    #pragma unroll
    for (int i = 0; i < 2; ++i) {
        const int k = w * 2 + i;
        const int row = 2 * k + (lane >> 5);
        const int gc = (lane & 31) ^ (row & 7);
        offk[i] = row * 1168 + gc * 4;
    }

    // stage leaf-x of mid mm into xbuf[mm&1]: this wave's chunks k=2w,2w+1
    auto stage = [&](int mm) {
        const float* bm_ = xbase + mm * 128;
        float* db = &xbuf[mm & 1][(w * 2) * 256];
        gl_lds16(bm_ + offk[0], db);
        gl_lds16(bm_ + offk[1], db + 256);
    };

    // zero pad-K cols 144..159 of mid_in (once; read by mid K-step s=4;
    // A' rows there are 0, but 0*garbage = NaN without this)
    if (w == 1) {
        uint2 z; z.x = 0u; z.y = 0u;
        *(uint2*)&mid_in[c][144 + 4 * g] = z;
    }

    // ---- prologue: stage xtail (cols 1024..1168, once) + stages 0,1 --------
    #pragma unroll
    for (int i = 0; i < 2; ++i) {
        const int kk = w + 4 * i;
        const int gi = kk * 64 + lane;
        const int row = gi / 36, col = gi - row * 36;
        gl_lds16(xbase + row * 1168 + 1024 + col * 4, &xtail[kk * 256]);
    }
    if (w == 0) {
        const int gi = 8 * 64 + lane;
        const int row = gi / 36, col = gi - row * 36;
        gl_lds16(xbase + row * 1168 + 1024 + col * 4, &xtail[8 * 256]);
    }
    stage(0);
    stage(1);
    asm volatile("s_waitcnt vmcnt(2) lgkmcnt(0)" ::: "memory");  // xtail+stage0 done (own)
    BARRIER();

    // ---- root K-step 0 from xtail (x cols 1152..1167; A' rows k>=16 are 0) --
    f32x4 accR;
    {
        const float* rp = &xtail[(c * 36 + 32 + 2 * (g & 1)) * 4];
        float4 xa = *(const float4*)rp;
        float4 xb = *(const float4*)(rp + 4);
        bf16x8 bfrag = pack8(xa, xb);
        bf16x8 a = *(const bf16x8*)(wsFrag + (WSB_ROOT + w * 9) * 512 + lane * 8);
        f32x4 zz = {0.f, 0.f, 0.f, 0.f};
        accR = __builtin_amdgcn_mfma_f32_16x16x32_bf16(a, bfrag, zz, 0, 0, 0);
    }

    #pragma unroll 1
    for (int m = 0; m < 8; ++m) {
        // entering: stage m resident; hm[(m-1)&1] ready (m>0)
        if (m > 0) {   // root K-step m (col-tile w)
            bf16x8 bfrag = *(const bf16x8*)&hm[(m - 1) & 1][c][g * 8];
            bf16x8 a = *(const bf16x8*)(wsFrag + (WSB_ROOT + w * 9 + m) * 512 + lane * 8);
            accR = __builtin_amdgcn_mfma_f32_16x16x32_bf16(a, bfrag, accR, 0, 0, 0);
        }
        // ---- leaves: pair w -> leaves 2w, 2w+1 of mid m ----
        {
            const float* xb_ = &xbuf[m & 1][0];
            const int G0 = w * 8 + g * 2;
            float4 xa = *(const float4*)(xb_ + (c * 32 + (G0 ^ (c & 7))) * 4);
            float4 x2 = *(const float4*)(xb_ + (c * 32 + ((G0 + 1) ^ (c & 7))) * 4);
            bf16x8 bfrag = pack8(xa, x2);
            #pragma unroll
            for (int e = 0; e < 2; ++e) {
                const int leaf = m * 8 + 2 * w + e;
                bf16x8 afrag = *(const bf16x8*)(wsFrag + (WSB_LEAF + leaf) * 512 + lane * 8);
                f32x4 zz = {0.f, 0.f, 0.f, 0.f};
                f32x4 acc = __builtin_amdgcn_mfma_f32_16x16x32_bf16(afrag, bfrag, zz, 0, 0, 0);
                const int po = leaf * 16 + 4 * g;
                float4 S = *(const float4*)(Sl + po);
                float4 T = *(const float4*)(Tl + po);
                float h0 = bn_act(acc[0], S.x, T.x);
                float h1 = bn_act(acc[1], S.y, T.y);
                float h2 = bn_act(acc[2], S.z, T.z);
                float h3 = bn_act(acc[3], S.w, T.w);
                uint2 pk; pk.x = pack2bf(h0, h1); pk.y = pack2bf(h2, h3);
                *(uint2*)&mid_in[c][16 + (2 * w + e) * 16 + 4 * g] = pk;
            }
        }
        if (w == 0) {   // xm -> mid_in cols 0..15
            const float* xmp = &xtail[(c * 36 + m * 4 + g) * 4];
            float4 xm4 = *(const float4*)xmp;
            uint2 pm; pm.x = pack2bf(xm4.x, xm4.y); pm.y = pack2bf(xm4.z, xm4.w);
            *(uint2*)&mid_in[c][4 * g] = pm;
        }
        asm volatile("s_waitcnt lgkmcnt(0)" ::: "memory");
        BARRIER();   // barrier B: mid_in ready; all xbuf[m&1] reads done

        if (m + 2 < 8) stage(m + 2);   // safe: overwrites xbuf[m&1] post-reads

        if (w >= 2) {   // mid col-tile tt = w-2: 5 K-steps
            const int tt = w - 2;
            f32x4 acc = {0.f, 0.f, 0.f, 0.f};
            const unsigned short* fb =
                wsFrag + (WSB_MID + m * 10 + tt * 5) * 512 + lane * 8;
            #pragma unroll
            for (int s = 0; s < 5; ++s) {
                bf16x8 bfrag = *(const bf16x8*)&mid_in[c][s * 32 + g * 8];
                bf16x8 a0 = *(const bf16x8*)(fb + s * 512);
                acc = __builtin_amdgcn_mfma_f32_16x16x32_bf16(a0, bfrag, acc, 0, 0, 0);
            }
            const int po = m * 32 + tt * 16 + 4 * g;
            float4 S = *(const float4*)(Sm + po);
            float4 T = *(const float4*)(Tm + po);
            float h0 = bn_act(acc[0], S.x, T.x);
            float h1 = bn_act(acc[1], S.y, T.y);
            float h2 = bn_act(acc[2], S.z, T.z);
            float h3 = bn_act(acc[3], S.w, T.w);
            uint2 pk; pk.x = pack2bf(h0, h1); pk.y = pack2bf(h2, h3);
            *(uint2*)&hm[m & 1][c][tt * 16 + 4 * g] = pk;
        }
        // stage m+1 done (own): 2 newer (s_{m+2}) may remain; tail drains all
        if (m < 6) { asm volatile("s_waitcnt vmcnt(2)" ::: "memory"); }
        else       { asm volatile("s_waitcnt vmcnt(0)" ::: "memory"); }
        asm volatile("s_waitcnt lgkmcnt(0)" ::: "memory");
        BARRIER();   // barrier A': stage m+1 visible; hm[m&1] ready
    }

    // ---- final root K-step 8 (from hm[1]) + BN + hr ------------------------
    {
        bf16x8 bfrag = *(const bf16x8*)&hm[1][c][g * 8];
        bf16x8 a = *(const bf16x8*)(wsFrag + (WSB_ROOT + w * 9 + 8) * 512 + lane * 8);
        accR = __builtin_amdgcn_mfma_f32_16x16x32_bf16(a, bfrag, accR, 0, 0, 0);
        const int po = w * 16 + 4 * g;
        float4 S = *(const float4*)(Sr + po);
        float4 T = *(const float4*)(Tr + po);
        float h0 = bn_act(accR[0], S.x, T.x);
        float h1 = bn_act(accR[1], S.y, T.y);
        float h2 = bn_act(accR[2], S.z, T.z);
        float h3 = bn_act(accR[3], S.w, T.w);
        uint2 pk; pk.x = pack2bf(h0, h1); pk.y = pack2bf(h2, h3);
        *(uint2*)&hr[c][po] = pk;
    }
    asm volatile("s_waitcnt lgkmcnt(0)" ::: "memory");
    BARRIER();

    // ---- head (wave 0): tasks in rows, samples in cols ---------------------
    if (w == 0) {
        f32x4 acc = {0.f, 0.f, 0.f, 0.f};
        #pragma unroll
        for (int s = 0; s < 2; ++s) {
            bf16x8 bfrag = *(const bf16x8*)&hr[c][s * 32 + g * 8];
            bf16x8 a0 = *(const bf16x8*)(wsFrag + (WSB_HEAD + s) * 512 + lane * 8);
            acc = __builtin_amdgcn_mfma_f32_16x16x32_bf16(a0, bfrag, acc, 0, 0, 0);
        }
        float* op = out + (size_t)(rowbase + c) * 10 + 4 * g;
        if (g < 2) {
            float2 o1 = {acc[0] + bh[4 * g],     acc[1] + bh[4 * g + 1]};
            float2 o2 = {acc[2] + bh[4 * g + 2], acc[3] + bh[4 * g + 3]};
            *(float2*)op = o1;
            *(float2*)(op + 2) = o2;
        } else if (g == 2) {
            float2 o1 = {acc[0] + bh[8], acc[1] + bh[9]};
            *(float2*)op = o1;
        }
    }
}

extern "C" void kernel_launch(void* const* d_in, const int* in_sizes, int n_in,
                              void* d_out, int out_size, void* d_ws, size_t ws_size,
                              hipStream_t stream) {
    const float* x     = (const float*)d_in[0];
    const float* Wl    = (const float*)d_in[1];
    const float* bl    = (const float*)d_in[2];
    const float* gl    = (const float*)d_in[3];
    const float* betal = (const float*)d_in[4];
    const float* ml    = (const float*)d_in[5];
    const float* vl    = (const float*)d_in[6];
    const float* Wm    = (const float*)d_in[7];
    const float* bm    = (const float*)d_in[8];
    const float* gm    = (const float*)d_in[9];
    const float* betam = (const float*)d_in[10];
    const float* mm    = (const float*)d_in[11];
    const float* vm    = (const float*)d_in[12];
    const float* Wr    = (const float*)d_in[13];
    const float* br    = (const float*)d_in[14];
    const float* gr    = (const float*)d_in[15];
    const float* betar = (const float*)d_in[16];
    const float* mr    = (const float*)d_in[17];
    const float* vr    = (const float*)d_in[18];
    const float* Wh    = (const float*)d_in[19];
    const float* bh    = (const float*)d_in[20];
    float* out = (float*)d_out;

    unsigned short* wsFrag = (unsigned short*)d_ws;
    float* wsST = (float*)((char*)d_ws + WS_ST_BYTE_OFF);

    ontology_prep<<<N_FRAG_BLOCKS + 3, 64, 0, stream>>>(
        Wl, Wm, Wr, Wh, bl, gl, betal, ml, vl, bm, gm, betam, mm, vm,
        br, gr, betar, mr, vr, wsFrag, wsST);

    const int n = in_sizes[0] / 1168;   // 16384
    ontology_mfma<<<n / 16, 256, 0, stream>>>(x, wsFrag, wsST, bh, out);
}

// Round 8
// 31.606 us; speedup vs baseline: 1.1923x; 1.1923x over previous
//
#include <hip/hip_runtime.h>

typedef __attribute__((ext_vector_type(8))) short bf16x8;
typedef __attribute__((ext_vector_type(4))) float f32x4;

#define EPS 1e-5f
#define K2L 2.8853900817779268f   // 2*log2(e): folds exp(2y) -> exp2(y*K2L)

// ws layout: frag blocks (182 x 1KB bf16) then fp32 ST region
#define N_FRAG_BLOCKS 182
#define WSB_LEAF 0      // 64 blocks: leaf l
#define WSB_MID  64     // 80 blocks: m*10 + tt*5 + s
#define WSB_ROOT 144    // 36 blocks: tt*9 + s
#define WSB_HEAD 180    // 2 blocks: s
#define ST_SL 0
#define ST_TL 1024
#define ST_SM 2048
#define ST_TM 2304
#define ST_SR 2560
#define ST_TR 2624
#define WS_ST_BYTE_OFF (N_FRAG_BLOCKS * 1024)

__device__ __forceinline__ unsigned short f2bf(float f) {  // RNE float->bf16
    unsigned u = __float_as_uint(f);
    unsigned r = u + 0x7fffu + ((u >> 16) & 1u);
    return (unsigned short)(r >> 16);
}

__device__ __forceinline__ unsigned pack2bf(float a, float b) {
    return (unsigned)f2bf(a) | ((unsigned)f2bf(b) << 16);
}

__device__ __forceinline__ bf16x8 pack8(float4 a, float4 b) {
    union { unsigned u[4]; bf16x8 v; } r;
    r.u[0] = pack2bf(a.x, a.y); r.u[1] = pack2bf(a.z, a.w);
    r.u[2] = pack2bf(b.x, b.y); r.u[3] = pack2bf(b.z, b.w);
    return r.v;
}

// BN+tanh with pre-folded scale: arg = acc*S' + T' (S',T' carry 2*log2e)
__device__ __forceinline__ float bn_act(float acc, float Sp, float Tp) {
    float e = exp2f(fmaf(acc, Sp, Tp));
    float r = __builtin_amdgcn_rcpf(e + 1.0f);
    return fmaf(-2.0f, r, 1.0f);
}

// ---------------- prep: fragment-ordered bf16 weights + folded BN ----------
__global__ void ontology_prep(
    const float* __restrict__ Wl, const float* __restrict__ Wm,
    const float* __restrict__ Wr, const float* __restrict__ Wh,
    const float* __restrict__ bl, const float* __restrict__ gl,
    const float* __restrict__ betal, const float* __restrict__ ml,
    const float* __restrict__ vl,
    const float* __restrict__ bm, const float* __restrict__ gm,
    const float* __restrict__ betam, const float* __restrict__ mm,
    const float* __restrict__ vm,
    const float* __restrict__ br, const float* __restrict__ gr,
    const float* __restrict__ betar, const float* __restrict__ mr,
    const float* __restrict__ vr,
    unsigned short* __restrict__ wsFrag, float* __restrict__ wsST)
{
    const int b = blockIdx.x;
    const int t = threadIdx.x;
    if (b < N_FRAG_BLOCKS) {
        // A'-frag (transposed weights): lane t holds A'[row=t&15][k=(t>>4)*8+i]
        const int row = t & 15, g = t >> 4;
        unsigned short vals[8];
        #pragma unroll
        for (int i = 0; i < 8; ++i) {
            const int k = g * 8 + i;
            float v = 0.f;
            if (b < 64) {                       // leaf l: pair-packed K
                const int l = b;
                if ((l & 1) == 0) { if (k < 16)  v = Wl[l * 256 + k * 16 + row]; }
                else              { if (k >= 16) v = Wl[l * 256 + (k - 16) * 16 + row]; }
            } else if (b < 144) {               // mid: m*10 + tt*5 + s
                const int idx = b - 64, m = idx / 10, rem = idx % 10;
                const int tt = rem / 5, s = rem % 5;
                const int krow = s * 32 + k;
                if (krow < 144) v = Wm[m * 4608 + krow * 32 + tt * 16 + row];
            } else if (b < 180) {               // root: tt*9 + s
                const int idx = b - 144, tt = idx / 9, s = idx % 9;
                if (s == 0) { if (k < 16) v = Wr[k * 64 + tt * 16 + row]; }
                else { const int krow = 16 + (s - 1) * 32 + k;
                       v = Wr[krow * 64 + tt * 16 + row]; }
            } else {                            // head
                const int s = b - 180, krow = s * 32 + k;
                if (row < 10) v = Wh[krow * 10 + row];
            }
            vals[i] = f2bf(v);
        }
        #pragma unroll
        for (int i = 0; i < 8; ++i) wsFrag[b * 512 + t * 8 + i] = vals[i];
    } else if (b == N_FRAG_BLOCKS) {            // leaf ST (1024), folded by K2L
        for (int i = 0; i < 16; ++i) {
            const int id = t + 64 * i;
            const float S = gl[id] * rsqrtf(vl[id] + EPS);
            wsST[ST_SL + id] = S * K2L;
            wsST[ST_TL + id] = ((bl[id] - ml[id]) * S + betal[id]) * K2L;
        }
    } else if (b == N_FRAG_BLOCKS + 1) {        // mid ST (256)
        for (int i = 0; i < 4; ++i) {
            const int id = t + 64 * i;
            const float S = gm[id] * rsqrtf(vm[id] + EPS);
            wsST[ST_SM + id] = S * K2L;
            wsST[ST_TM + id] = ((bm[id] - mm[id]) * S + betam[id]) * K2L;
        }
    } else {                                     // root ST (64)
        const int id = t;
        const float S = gr[id] * rsqrtf(vr[id] + EPS);
        wsST[ST_SR + id] = S * K2L;
        wsST[ST_TR + id] = ((br[id] - mr[id]) * S + betar[id]) * K2L;
    }
}

// ---------------- main fused MFMA kernel: independent waves ----------------
// Block = 256 thr = 4 waves = one 16-sample tile. Wave w is SELF-CONTAINED
// for mids {w, w+4}: 8 leaves -> mid -> root K-partial, all intra-wave LDS
// deps (compiler lgkmcnt), ZERO barriers in the main loop. Cross-wave root
// K-sum at the end via f32 LDS slab, 2 deterministic rounds. 4 barriers total.
// Grid 1024 x 4 waves = 4096 waves = one full resident generation (16/CU).
__global__ __launch_bounds__(256, 4) void ontology_mfma(
    const float* __restrict__ x,
    const unsigned short* __restrict__ wsFrag,
    const float* __restrict__ wsST,
    const float* __restrict__ bh,
    float* __restrict__ out)
{
    __shared__ __align__(16) unsigned short mid_in[4][16][168]; // 21.0 KB (per wave)
    __shared__ __align__(16) unsigned short hm[4][16][40];      //  2.5 KB (per wave)
    __shared__ __align__(16) float slab[4][16][34];             //  8.5 KB (2-round)
    unsigned short (*hr)[72] = (unsigned short (*)[72])&mid_in[0][0][0]; // alias (dead)

    const int tid  = threadIdx.x;
    const int w    = tid >> 6;
    const int lane = tid & 63;
    const int c    = lane & 15;       // sample within tile
    const int g    = lane >> 4;       // k/feat group
    const int rowbase = blockIdx.x * 16;
    const float* xrow = x + (size_t)(rowbase + c) * 1168;

    const float* Sl = wsST + ST_SL; const float* Tl = wsST + ST_TL;
    const float* Sm = wsST + ST_SM; const float* Tm = wsST + ST_TM;
    const float* Sr = wsST + ST_SR; const float* Tr = wsST + ST_TR;

    // zero own K-pad cols 144..159 (read by mid s=4; own-wave dep, no barrier)
    { uint2 z; z.x = 0u; z.y = 0u; *(uint2*)&mid_in[w][c][144 + 4 * g] = z; }

    f32x4 accR[4];
    #pragma unroll
    for (int t = 0; t < 4; ++t) { f32x4 z0 = {0.f,0.f,0.f,0.f}; accR[t] = z0; }

    if (w == 3) {   // root K-step s=0 (x cols 1152..; A' rows k>=16 are 0)
        const float* rp = xrow + 1152 + (g & 1) * 8;
        bf16x8 bfrag = pack8(*(const float4*)rp, *(const float4*)(rp + 4));
        #pragma unroll
        for (int t = 0; t < 4; ++t) {
            bf16x8 a = *(const bf16x8*)(wsFrag + (WSB_ROOT + t * 9) * 512 + lane * 8);
            accR[t] = __builtin_amdgcn_mfma_f32_16x16x32_bf16(a, bfrag, accR[t], 0, 0, 0);
        }
    }

    #pragma unroll
    for (int it = 0; it < 2; ++it) {
        const int M = w + 4 * it;                 // this wave's mid (uniform)
        // ---- x loads for the whole phase (9 float4) ----
        float4 xm4 = *(const float4*)(xrow + 1024 + M * 16 + 4 * g);
        float4 xp[4][2];
        #pragma unroll
        for (int p = 0; p < 4; ++p) {
            const float* a = xrow + (M * 4 + p) * 32 + g * 8;
            xp[p][0] = *(const float4*)a;
            xp[p][1] = *(const float4*)(a + 4);
        }
        // ---- leaf A-frags (8, independent L2 loads) ----
        bf16x8 lfr[8];
        #pragma unroll
        for (int l = 0; l < 8; ++l)
            lfr[l] = *(const bf16x8*)(wsFrag + (WSB_LEAF + M * 8 + l) * 512 + lane * 8);
        // ---- xm -> mid_in cols 0..15 ----
        { uint2 pm; pm.x = pack2bf(xm4.x, xm4.y); pm.y = pack2bf(xm4.z, xm4.w);
          *(uint2*)&mid_in[w][c][4 * g] = pm; }
        // ---- 8 leaves ----
        #pragma unroll
        for (int p = 0; p < 4; ++p) {
            bf16x8 bfrag = pack8(xp[p][0], xp[p][1]);
            #pragma unroll
            for (int e = 0; e < 2; ++e) {
                const int l = 2 * p + e, leaf = M * 8 + l;
                f32x4 zz = {0.f,0.f,0.f,0.f};
                f32x4 acc = __builtin_amdgcn_mfma_f32_16x16x32_bf16(lfr[l], bfrag, zz, 0, 0, 0);
                const int po = leaf * 16 + 4 * g;
                float4 S = *(const float4*)(Sl + po);
                float4 T = *(const float4*)(Tl + po);
                float h0 = bn_act(acc[0], S.x, T.x);
                float h1 = bn_act(acc[1], S.y, T.y);
                float h2 = bn_act(acc[2], S.z, T.z);
                float h3 = bn_act(acc[3], S.w, T.w);
                uint2 pk; pk.x = pack2bf(h0, h1); pk.y = pack2bf(h2, h3);
                *(uint2*)&mid_in[w][c][16 + l * 16 + 4 * g] = pk;
            }
        }
        // ---- mid M: 2 col-tiles x 5 K-steps (reads own mid_in) ----
        #pragma unroll
        for (int tt = 0; tt < 2; ++tt) {
            f32x4 acc = {0.f,0.f,0.f,0.f};
            const unsigned short* fb = wsFrag + (WSB_MID + M * 10 + tt * 5) * 512 + lane * 8;
            #pragma unroll
            for (int s = 0; s < 5; ++s) {
                bf16x8 bfrag = *(const bf16x8*)&mid_in[w][c][s * 32 + g * 8];
                bf16x8 a0 = *(const bf16x8*)(fb + s * 512);
                acc = __builtin_amdgcn_mfma_f32_16x16x32_bf16(a0, bfrag, acc, 0, 0, 0);
            }
            const int po = M * 32 + tt * 16 + 4 * g;
            float4 S = *(const float4*)(Sm + po);
            float4 T = *(const float4*)(Tm + po);
            float h0 = bn_act(acc[0], S.x, T.x);
            float h1 = bn_act(acc[1], S.y, T.y);
            float h2 = bn_act(acc[2], S.z, T.z);
            float h3 = bn_act(acc[3], S.w, T.w);
            uint2 pk; pk.x = pack2bf(h0, h1); pk.y = pack2bf(h2, h3);
            *(uint2*)&hm[w][c][tt * 16 + 4 * g] = pk;
        }
        // ---- root K-partial s = M+1 (reads own hm) ----
        {
            bf16x8 bfrag = *(const bf16x8*)&hm[w][c][g * 8];
            #pragma unroll
            for (int t = 0; t < 4; ++t) {
                bf16x8 a = *(const bf16x8*)(wsFrag + (WSB_ROOT + t * 9 + M + 1) * 512 + lane * 8);
                accR[t] = __builtin_amdgcn_mfma_f32_16x16x32_bf16(a, bfrag, accR[t], 0, 0, 0);
            }
        }
    }

    // ---- cross-wave root combine, round A (col-tiles 0,1) ------------------
    #pragma unroll
    for (int t = 0; t < 2; ++t) {
        float2 lo; lo.x = accR[t][0]; lo.y = accR[t][1];
        float2 hi; hi.x = accR[t][2]; hi.y = accR[t][3];
        *(float2*)&slab[w][c][t * 16 + 4 * g]     = lo;
        *(float2*)&slab[w][c][t * 16 + 4 * g + 2] = hi;
    }
    asm volatile("s_waitcnt lgkmcnt(0)" ::: "memory");
    __builtin_amdgcn_s_barrier();
    if (w < 2) {
        float4 sum = {0.f,0.f,0.f,0.f};
        #pragma unroll
        for (int v = 0; v < 4; ++v) {
            float2 lo = *(const float2*)&slab[v][c][w * 16 + 4 * g];
            float2 hi = *(const float2*)&slab[v][c][w * 16 + 4 * g + 2];
            sum.x += lo.x; sum.y += lo.y; sum.z += hi.x; sum.w += hi.y;
        }
        const int po = w * 16 + 4 * g;
        float4 S = *(const float4*)(Sr + po);
        float4 T = *(const float4*)(Tr + po);
        uint2 pk;
        pk.x = pack2bf(bn_act(sum.x, S.x, T.x), bn_act(sum.y, S.y, T.y));
        pk.y = pack2bf(bn_act(sum.z, S.z, T.z), bn_act(sum.w, S.w, T.w));
        *(uint2*)&hr[c][po] = pk;   // hr aliases mid_in (dead after loop)
    }
    asm volatile("s_waitcnt lgkmcnt(0)" ::: "memory");
    __builtin_amdgcn_s_barrier();

    // ---- round B (col-tiles 2,3 at slab positions 0,1) ---------------------
    #pragma unroll
    for (int t = 2; t < 4; ++t) {
        float2 lo; lo.x = accR[t][0]; lo.y = accR[t][1];
        float2 hi; hi.x = accR[t][2]; hi.y = accR[t][3];
        *(float2*)&slab[w][c][(t - 2) * 16 + 4 * g]     = lo;
        *(float2*)&slab[w][c][(t - 2) * 16 + 4 * g + 2] = hi;
    }
    asm volatile("s_waitcnt lgkmcnt(0)" ::: "memory");
    __builtin_amdgcn_s_barrier();
    if (w >= 2) {
        float4 sum = {0.f,0.f,0.f,0.f};
        #pragma unroll
        for (int v = 0; v < 4; ++v) {
            float2 lo = *(const float2*)&slab[v][c][(w - 2) * 16 + 4 * g];
            float2 hi = *(const float2*)&slab[v][c][(w - 2) * 16 + 4 * g + 2];
            sum.x += lo.x; sum.y += lo.y; sum.z += hi.x; sum.w += hi.y;
        }
        const int po = w * 16 + 4 * g;
        float4 S = *(const float4*)(Sr + po);
        float4 T = *(const float4*)(Tr + po);
        uint2 pk;
        pk.x = pack2bf(bn_act(sum.x, S.x, T.x), bn_act(sum.y, S.y, T.y));
        pk.y = pack2bf(bn_act(sum.z, S.z, T.z), bn_act(sum.w, S.w, T.w));
        *(uint2*)&hr[c][po] = pk;
    }
    asm volatile("s_waitcnt lgkmcnt(0)" ::: "memory");
    __builtin_amdgcn_s_barrier();

    // ---- head (wave 0): tasks in rows, samples in cols ---------------------
    if (w == 0) {
        f32x4 acc = {0.f,0.f,0.f,0.f};
        #pragma unroll
        for (int s = 0; s < 2; ++s) {
            bf16x8 bfrag = *(const bf16x8*)&hr[c][s * 32 + g * 8];
            bf16x8 a0 = *(const bf16x8*)(wsFrag + (WSB_HEAD + s) * 512 + lane * 8);
            acc = __builtin_amdgcn_mfma_f32_16x16x32_bf16(a0, bfrag, acc, 0, 0, 0);
        }
        float* op = out + (size_t)(rowbase + c) * 10 + 4 * g;
        if (g < 2) {
            float2 o1 = {acc[0] + bh[4 * g],     acc[1] + bh[4 * g + 1]};
            float2 o2 = {acc[2] + bh[4 * g + 2], acc[3] + bh[4 * g + 3]};
            *(float2*)op = o1;
            *(float2*)(op + 2) = o2;
        } else if (g == 2) {
            float2 o1 = {acc[0] + bh[8], acc[1] + bh[9]};
            *(float2*)op = o1;
        }
    }
}

extern "C" void kernel_launch(void* const* d_in, const int* in_sizes, int n_in,
                              void* d_out, int out_size, void* d_ws, size_t ws_size,
                              hipStream_t stream) {
    const float* x     = (const float*)d_in[0];
    const float* Wl    = (const float*)d_in[1];
    const float* bl    = (const float*)d_in[2];
    const float* gl    = (const float*)d_in[3];
    const float* betal = (const float*)d_in[4];
    const float* ml    = (const float*)d_in[5];
    const float* vl    = (const float*)d_in[6];
    const float* Wm    = (const float*)d_in[7];
    const float* bm    = (const float*)d_in[8];
    const float* gm    = (const float*)d_in[9];
    const float* betam = (const float*)d_in[10];
    const float* mm    = (const float*)d_in[11];
    const float* vm    = (const float*)d_in[12];
    const float* Wr    = (const float*)d_in[13];
    const float* br    = (const float*)d_in[14];
    const float* gr    = (const float*)d_in[15];
    const float* betar = (const float*)d_in[16];
    const float* mr    = (const float*)d_in[17];
    const float* vr    = (const float*)d_in[18];
    const float* Wh    = (const float*)d_in[19];
    const float* bh    = (const float*)d_in[20];
    float* out = (float*)d_out;

    unsigned short* wsFrag = (unsigned short*)d_ws;
    float* wsST = (float*)((char*)d_ws + WS_ST_BYTE_OFF);

    ontology_prep<<<N_FRAG_BLOCKS + 3, 64, 0, stream>>>(
        Wl, Wm, Wr, Wh, bl, gl, betal, ml, vl, bm, gm, betam, mm, vm,
        br, gr, betar, mr, vr, wsFrag, wsST);

    const int n = in_sizes[0] / 1168;   // 16384
    ontology_mfma<<<n / 16, 256, 0, stream>>>(x, wsFrag, wsST, bh, out);
}